// Round 11
// baseline (230.261 us; speedup 1.0000x reference)
//
#include <hip/hip_runtime.h>
#include <hip/hip_bf16.h>
#include <cstdint>

typedef __bf16 bf16x8 __attribute__((ext_vector_type(8)));
typedef float  f32x4  __attribute__((ext_vector_type(4)));

#define S_LEN 4096
#define D_EMB 1024
#define N3    3072
#define HDIM  64

__device__ __forceinline__ unsigned short f2bf(float f) {
    union { unsigned int i; float f; } v; v.f = f;
    unsigned int i = v.i;
    return (unsigned short)((i + 0x7FFFu + ((i >> 16) & 1u)) >> 16);
}

// raw 2^x (1 ulp, same HW op __expf uses after its own log2e mul)
__device__ __forceinline__ float vexp2(float x) {
    float r; asm("v_exp_f32 %0, %1" : "=v"(r) : "v"(x)); return r;
}

// pack 2 fp32 -> 2 bf16, round-half-up: (u+0x8000)>>16. Max error 0.5 ulp.
__device__ __forceinline__ unsigned int pkbf(float lo, float hi) {
    union { float f; unsigned int u; } a, b; a.f = lo; b.f = hi;
    return ((a.u + 0x8000u) >> 16) | ((b.u + 0x8000u) & 0xFFFF0000u);
}

// async global->LDS, 16B/lane; LDS dest must be wave-uniform base + lane*16.
__device__ __forceinline__ void async16(const void* g, void* l) {
    __builtin_amdgcn_global_load_lds(
        (const __attribute__((address_space(1))) unsigned int*)g,
        (__attribute__((address_space(3))) unsigned int*)l,
        16, 0, 0);
}

// fp32 -> bf16 bulk convert, 8 elems/thread
__global__ void convert_f32_bf16(const float* __restrict__ src,
                                 unsigned short* __restrict__ dst, int n8) {
    const int i = blockIdx.x * blockDim.x + threadIdx.x;
    if (i >= n8) return;
    float4 f0 = *(const float4*)&src[i * 8];
    float4 f1 = *(const float4*)&src[i * 8 + 4];
    union { uint4 q; unsigned short s[8]; } o;
    o.s[0]=f2bf(f0.x); o.s[1]=f2bf(f0.y); o.s[2]=f2bf(f0.z); o.s[3]=f2bf(f0.w);
    o.s[4]=f2bf(f1.x); o.s[5]=f2bf(f1.y); o.s[6]=f2bf(f1.z); o.s[7]=f2bf(f1.w);
    *(uint4*)&dst[i * 8] = o.q;
}

// dst[c][r] = bf16(src[r*ld + c0 + c]);  src fp32, dst bf16 [C_][R]
__global__ void transpose_f32_to_bf16(const float* __restrict__ src,
                                      unsigned short* __restrict__ dst,
                                      int R, int ld, int c0) {
    __shared__ float tile[32][33];
    const int tx = threadIdx.x, ty = threadIdx.y;
    const int r0 = blockIdx.y * 32, cc0 = blockIdx.x * 32;
    for (int i = 0; i < 32; i += 8)
        tile[ty + i][tx] = src[(size_t)(r0 + ty + i) * ld + c0 + cc0 + tx];
    __syncthreads();
    for (int i = 0; i < 32; i += 8)
        dst[(size_t)(cc0 + ty + i) * R + r0 + tx] = f2bf(tile[tx][ty + i]);
}

// dst[c][r] = src[r*ld + c0 + c];  bf16 -> bf16, dst [C_][R]
__global__ void transpose_bf16(const unsigned short* __restrict__ src,
                               unsigned short* __restrict__ dst,
                               int R, int ld, int c0) {
    __shared__ unsigned short tile[32][33];
    const int tx = threadIdx.x, ty = threadIdx.y;
    const int r0 = blockIdx.y * 32, cc0 = blockIdx.x * 32;
    for (int i = 0; i < 32; i += 8)
        tile[ty + i][tx] = src[(size_t)(r0 + ty + i) * ld + c0 + cc0 + tx];
    __syncthreads();
    for (int i = 0; i < 32; i += 8)
        dst[(size_t)(cc0 + ty + i) * R + r0 + tx] = tile[tx][ty + i];
}

// ---------- 128-class GEMM (r8 champion form) — used for GEMM2 ----------
// C[M,N] = A[M,K] @ BT[N,K]^T + bias[N]. 2-buffer pipelined staging:
// stage(t+1) before compute(t); the __syncthreads vmcnt(0) drain lands
// after the compute phase. r9's counted-vmcnt 3-buffer graft was negative.
template <bool OUT_F32, int BM>
__global__ __launch_bounds__(256) void gemm_bt_bias(
    const unsigned short* __restrict__ A,
    const unsigned short* __restrict__ BT,
    const float* __restrict__ bias,
    void* __restrict__ Cp,
    int M, int N, int K)
{
    constexpr int MI = BM / 32;   // 16-row fragments per wave (4 or 2)
    __shared__ __align__(16) unsigned short As[2][BM * 32];
    __shared__ __align__(16) unsigned short Bs[2][128 * 32];
    const int tid  = threadIdx.x;
    const int wave = tid >> 6, lane = tid & 63;
    const int q4 = lane >> 4, l16 = lane & 15;
    const int m0 = blockIdx.y * BM, n0 = blockIdx.x * 128;
    const int wm = (wave >> 1) * (BM / 2), wn = (wave & 1) * 64;

    f32x4 acc[MI][4] = {};

    const int srowA = wave * (BM / 4) + (lane >> 2);   // + i*16
    const int srowB = wave * 32 + (lane >> 2);         // + i*16
    const int scol  = (lane & 3) * 8;

    auto stage = [&](int buf, int k0) {
#pragma unroll
        for (int i = 0; i < BM / 64; ++i) {
            const int r = srowA + i * 16;
            async16(A + (size_t)(m0 + r) * K + k0 + scol,
                    &As[buf][(wave * (BM / 4) + i * 16) * 32 + lane * 8]);
        }
#pragma unroll
        for (int i = 0; i < 2; ++i) {
            const int r = srowB + i * 16;
            async16(BT + (size_t)(n0 + r) * K + k0 + scol,
                    &Bs[buf][(wave * 32 + i * 16) * 32 + lane * 8]);
        }
    };

    const int nt = K / 32;
    stage(0, 0);
    __syncthreads();

    int cur = 0;
    for (int t = 0; t < nt; ++t) {
        if (t + 1 < nt) stage(cur ^ 1, (t + 1) * 32);

        bf16x8 af[MI], bfr[4];
#pragma unroll
        for (int mi = 0; mi < MI; ++mi)
            af[mi] = *(const bf16x8*)&As[cur][(wm + mi * 16 + l16) * 32 + q4 * 8];
#pragma unroll
        for (int ni = 0; ni < 4; ++ni)
            bfr[ni] = *(const bf16x8*)&Bs[cur][(wn + ni * 16 + l16) * 32 + q4 * 8];
#pragma unroll
        for (int mi = 0; mi < MI; ++mi)
#pragma unroll
            for (int ni = 0; ni < 4; ++ni)
                acc[mi][ni] = __builtin_amdgcn_mfma_f32_16x16x32_bf16(
                    af[mi], bfr[ni], acc[mi][ni], 0, 0, 0);

        __syncthreads();
        cur ^= 1;
    }

#pragma unroll
    for (int ni = 0; ni < 4; ++ni) {
        const int col = n0 + wn + ni * 16 + l16;
        const float bv = bias[col];
#pragma unroll
        for (int mi = 0; mi < MI; ++mi) {
            const int row = m0 + wm + mi * 16 + q4 * 4;
#pragma unroll
            for (int r = 0; r < 4; ++r) {
                const float val = acc[mi][ni][r] + bv;
                if constexpr (OUT_F32)
                    ((float*)Cp)[(size_t)(row + r) * N + col] = val;
                else
                    ((unsigned short*)Cp)[(size_t)(row + r) * N + col] = f2bf(val);
            }
        }
    }
}

// ---------- 256x256 GEMM (round 11) — used for GEMM1 ----------
// Same verified 2-phase pipelined structure scaled to 256^2 / 8 waves
// (catalog: 256^2+2ph = 682 TF vs 622 at 128^2, m230/m228d). Per wave-step:
// 32 MFMA (vs 16) for the same 4 staging loads/thread and one barrier pair.
// Wave grid 2Mx4N, per-wave output 128x64 = acc[8][4] (~200 VGPR, 8 waves
// = 2/SIMD, 1 block/CU). LDS 2 x (16K A + 16K B) = 64 KB. Grid 12x16=192.
__global__ __launch_bounds__(512) void gemm_bt_bias_256(
    const unsigned short* __restrict__ A,
    const unsigned short* __restrict__ BT,
    const float* __restrict__ bias,
    unsigned short* __restrict__ C,
    int M, int N, int K)
{
    __shared__ __align__(16) unsigned short As[2][256 * 32];
    __shared__ __align__(16) unsigned short Bs[2][256 * 32];
    const int tid  = threadIdx.x;
    const int lane = tid & 63;
    const int wave = tid >> 6;                  // 0..7
    const int q4 = lane >> 4, l16 = lane & 15;
    const int m0 = blockIdx.y * 256, n0 = blockIdx.x * 256;
    const int wm = (wave >> 2) * 128, wn = (wave & 3) * 64;

    f32x4 acc[8][4] = {};

    // staging: 256 rows x 32 cols per operand; 1024 16B-segments; 2/thread.
    // segment s: row = s>>2, k = (s&3)*8; LDS offset = s*8 shorts (linear,
    // wave-uniform base + lane*16 since s = i*512 + wave*64 + lane).
    auto stage = [&](int buf, int k0) {
#pragma unroll
        for (int i = 0; i < 2; ++i) {
            const int s = i * 512 + tid;
            const int row = s >> 2, kc = (s & 3) * 8;
            async16(A  + (size_t)(m0 + row) * K + k0 + kc, &As[buf][s * 8]);
            async16(BT + (size_t)(n0 + row) * K + k0 + kc, &Bs[buf][s * 8]);
        }
    };

    const int nt = K / 32;
    stage(0, 0);
    __syncthreads();

    int cur = 0;
    for (int t = 0; t < nt; ++t) {
        if (t + 1 < nt) stage(cur ^ 1, (t + 1) * 32);

        bf16x8 af[8], bfr[4];
#pragma unroll
        for (int mi = 0; mi < 8; ++mi)
            af[mi] = *(const bf16x8*)&As[cur][(wm + mi * 16 + l16) * 32 + q4 * 8];
#pragma unroll
        for (int ni = 0; ni < 4; ++ni)
            bfr[ni] = *(const bf16x8*)&Bs[cur][(wn + ni * 16 + l16) * 32 + q4 * 8];
#pragma unroll
        for (int mi = 0; mi < 8; ++mi)
#pragma unroll
            for (int ni = 0; ni < 4; ++ni)
                acc[mi][ni] = __builtin_amdgcn_mfma_f32_16x16x32_bf16(
                    af[mi], bfr[ni], acc[mi][ni], 0, 0, 0);

        __syncthreads();
        cur ^= 1;
    }

    // epilogue: C/D layout col = lane&15, row = (lane>>4)*4 + reg; bf16 out
#pragma unroll
    for (int ni = 0; ni < 4; ++ni) {
        const int col = n0 + wn + ni * 16 + l16;
        const float bv = bias[col];
#pragma unroll
        for (int mi = 0; mi < 8; ++mi) {
            const int row = m0 + wm + mi * 16 + q4 * 4;
#pragma unroll
            for (int r = 0; r < 4; ++r)
                C[(size_t)(row + r) * N + col] = f2bf(acc[mi][ni][r] + bv);
        }
    }
}

// Causal flash attention, static-max softmax (scores ~N(0,0.17), |s|<~4).
// qkv [S][3072] bf16, Vt [1024][S] bf16, X2 [S][1024] bf16.
// Grid (64,16); q-tile remapped per head-group so the 4 co-resident blocks
// per CU have complementary causal work (130 kv-tiles per CU, balanced).
// EXACT round-10 champion (81.2 us): swapped QK^T -> packed uint2 P-writes,
// T14 register prefetch, vexp2 pre-folded scale, pair-pack bf16, mask
// unswitched to diagonal tile. Constraints: VGPR<=64, LDS 27.6K, K/V
// LDS-staged, no setprio, no per-wave q doubling.
#define LDP 72   // padded row stride (shorts): 144 B breaks the 128 B conflict
__global__ __launch_bounds__(256) void attn_flash(
    const unsigned short* __restrict__ qkv,
    const unsigned short* __restrict__ Vt,
    unsigned short* __restrict__ X2)
{
    __shared__ __align__(16) unsigned short Ks[64 * LDP];      // [kv][d]
    __shared__ __align__(16) unsigned short Vs[64 * LDP];      // [d][kv]
    __shared__ __align__(16) unsigned short Ps[4 * 16 * LDP];  // per-wave [16 q][64 kv]
    const int tid  = threadIdx.x;
    const int wave = tid >> 6, lane = tid & 63;
    const int q4 = lane >> 4, l16 = lane & 15;
    const int h  = blockIdx.y;

    // balanced q-tile mapping: head-group k gets {x, 63-x, x+16, 47-x}
    const int x = blockIdx.x, hg = blockIdx.y >> 2;
    int qt;
    if      (hg == 0) qt = x;
    else if (hg == 1) qt = 63 - x;
    else if (hg == 2) qt = (x + 16) & 63;
    else              qt = (47 - x) & 63;
    const int q0 = qt * 64;

    // Q frags (A/B layouts match: idx = lane&15, k = quad*8+j)
    bf16x8 aq[2];
    {
        const unsigned short* qp =
            qkv + (size_t)(q0 + wave * 16 + l16) * N3 + h * HDIM + q4 * 8;
        aq[0] = *(const bf16x8*)(qp);
        aq[1] = *(const bf16x8*)(qp + 32);
    }

    float l_part = 0.f;
    f32x4 o[4] = {};

    const int rr = tid >> 3;        // 0..31
    const int cc = (tid & 7) * 8;   // 0..56
    const int ntile = qt + 1;
    const int grow = q0 + wave * 16 + l16;   // this lane's q row (swapped layout)

    const float SCL = 0.18033688f;  // 0.125 * log2(e)

    // prefetch tile 0 into registers
    uint4 kv_a, kv_b, vt_a, vt_b;
    {
        kv_a = *(const uint4*)&qkv[(size_t)(rr)      * N3 + D_EMB + h * HDIM + cc];
        kv_b = *(const uint4*)&qkv[(size_t)(32 + rr) * N3 + D_EMB + h * HDIM + cc];
        vt_a = *(const uint4*)&Vt [(size_t)(h * HDIM + rr)      * S_LEN + cc];
        vt_b = *(const uint4*)&Vt [(size_t)(h * HDIM + 32 + rr) * S_LEN + cc];
    }

    for (int t = 0; t < ntile; ++t) {
        const int kv0 = t * 64;
        __syncthreads();   // prior tile's LDS reads complete
        *(uint4*)&Ks[rr * LDP + cc]        = kv_a;
        *(uint4*)&Ks[(32 + rr) * LDP + cc] = kv_b;
        *(uint4*)&Vs[rr * LDP + cc]        = vt_a;
        *(uint4*)&Vs[(32 + rr) * LDP + cc] = vt_b;
        // issue next tile's loads now; compute below hides their latency
        if (t + 1 < ntile) {
            const int kn = kv0 + 64;
            kv_a = *(const uint4*)&qkv[(size_t)(kn + rr)      * N3 + D_EMB + h * HDIM + cc];
            kv_b = *(const uint4*)&qkv[(size_t)(kn + 32 + rr) * N3 + D_EMB + h * HDIM + cc];
            vt_a = *(const uint4*)&Vt [(size_t)(h * HDIM + rr)      * S_LEN + kn + cc];
            vt_b = *(const uint4*)&Vt [(size_t)(h * HDIM + 32 + rr) * S_LEN + kn + cc];
        }
        __syncthreads();

        // S^T = K Q^T (A = K rows (m=kv), B = Q (n=q))
        f32x4 sacc[4] = {};
#pragma unroll
        for (int kk = 0; kk < 2; ++kk)
#pragma unroll
            for (int nt = 0; nt < 4; ++nt) {
                bf16x8 kf = *(const bf16x8*)&Ks[(nt * 16 + l16) * LDP + kk * 32 + q4 * 8];
                sacc[nt] = __builtin_amdgcn_mfma_f32_16x16x32_bf16(
                    kf, aq[kk], sacc[nt], 0, 0, 0);
            }

        // softmax-lite; mask only on the diagonal tile
        if (t != ntile - 1) {
#pragma unroll
            for (int nt = 0; nt < 4; ++nt) {
                float e0 = vexp2(sacc[nt][0] * SCL);
                float e1 = vexp2(sacc[nt][1] * SCL);
                float e2 = vexp2(sacc[nt][2] * SCL);
                float e3 = vexp2(sacc[nt][3] * SCL);
                l_part += e0; l_part += e1; l_part += e2; l_part += e3;
                uint2 pk;
                pk.x = pkbf(e0, e1);
                pk.y = pkbf(e2, e3);
                *(uint2*)&Ps[wave * 16 * LDP + l16 * LDP + nt * 16 + q4 * 4] = pk;
            }
        } else {
#pragma unroll
            for (int nt = 0; nt < 4; ++nt) {
                float e[4];
#pragma unroll
                for (int r = 0; r < 4; ++r) {
                    e[r] = vexp2(sacc[nt][r] * SCL);
                    if (kv0 + nt * 16 + q4 * 4 + r > grow) e[r] = 0.f;
                    l_part += e[r];
                }
                uint2 pk;
                pk.x = pkbf(e[0], e[1]);
                pk.y = pkbf(e[2], e[3]);
                *(uint2*)&Ps[wave * 16 * LDP + l16 * LDP + nt * 16 + q4 * 4] = pk;
            }
        }
        // per-wave LDS roundtrip: only need this wave's writes visible
        __asm__ volatile("s_waitcnt lgkmcnt(0)" ::: "memory");

        // O += P V
#pragma unroll
        for (int kk = 0; kk < 2; ++kk) {
            bf16x8 pa = *(const bf16x8*)&Ps[wave * 16 * LDP + l16 * LDP + kk * 32 + q4 * 8];
#pragma unroll
            for (int dt = 0; dt < 4; ++dt) {
                bf16x8 vb = *(const bf16x8*)&Vs[(dt * 16 + l16) * LDP + kk * 32 + q4 * 8];
                o[dt] = __builtin_amdgcn_mfma_f32_16x16x32_bf16(
                    pa, vb, o[dt], 0, 0, 0);
            }
        }
    }

    // row-sum: lane holds partial for q = l16; reduce across the 4 quads
    float l = l_part;
    l += __shfl_xor(l, 16);
    l += __shfl_xor(l, 32);
    float linv[4];
#pragma unroll
    for (int r = 0; r < 4; ++r)
        linv[r] = 1.f / __shfl(l, q4 * 4 + r);

#pragma unroll
    for (int dt = 0; dt < 4; ++dt)
#pragma unroll
        for (int r = 0; r < 4; ++r) {
            const int row = q0 + wave * 16 + q4 * 4 + r;
            X2[(size_t)row * D_EMB + h * HDIM + dt * 16 + l16] =
                f2bf(o[dt][r] * linv[r]);
        }
}

extern "C" void kernel_launch(void* const* d_in, const int* in_sizes, int n_in,
                              void* d_out, int out_size, void* d_ws, size_t ws_size,
                              hipStream_t stream) {
    const float* x     = (const float*)d_in[0];   // [4096][1024] fp32
    const float* w_qkv = (const float*)d_in[1];   // [1024][3072] fp32
    const float* b_qkv = (const float*)d_in[2];   // [3072] fp32
    const float* w_out = (const float*)d_in[3];   // [1024][1024] fp32
    const float* b_out = (const float*)d_in[4];   // [1024] fp32
    float* out = (float*)d_out;                   // [4096][1024] fp32

    char* ws = (char*)d_ws;
    unsigned short* qkv   = (unsigned short*)(ws);              // 24 MB
    unsigned short* wqkvT = (unsigned short*)(ws + 25165824);   //  6 MB
    unsigned short* woutT = (unsigned short*)(ws + 31457280);   //  2 MB
    unsigned short* Vt    = (unsigned short*)(ws + 33554432);   //  8 MB
    unsigned short* X2    = (unsigned short*)(ws + 41943040);   //  8 MB
    unsigned short* Xb    = X2;  // aliased: Xb consumed by GEMM1 before attn writes X2

    // x -> bf16
    convert_f32_bf16<<<(4096 * 1024 / 8 + 255) / 256, 256, 0, stream>>>(
        x, Xb, 4096 * 1024 / 8);

    // weight transposes + fp32->bf16 -> BT layout
    transpose_f32_to_bf16<<<dim3(3072 / 32, 1024 / 32), dim3(32, 8), 0, stream>>>(
        w_qkv, wqkvT, 1024, 3072, 0);
    transpose_f32_to_bf16<<<dim3(1024 / 32, 1024 / 32), dim3(32, 8), 0, stream>>>(
        w_out, woutT, 1024, 1024, 0);

    // qkv = Xb @ w_qkv + b_qkv  (bf16 out), 256x256 tiles, 8 waves
    gemm_bt_bias_256<<<dim3(3072 / 256, 4096 / 256), 512, 0, stream>>>(
        Xb, wqkvT, b_qkv, qkv, 4096, 3072, 1024);

    // Vt[h*64+d][s] = V[s][h*64+d]
    transpose_bf16<<<dim3(1024 / 32, 4096 / 32), dim3(32, 8), 0, stream>>>(
        qkv, Vt, 4096, 3072, 2048);

    // causal flash attention -> X2 [S][1024] bf16
    attn_flash<<<dim3(64, 16), 256, 0, stream>>>(qkv, Vt, X2);

    // out = X2 @ w_out + b_out  (fp32 out), 64x128 tiles, pipelined (r8)
    gemm_bt_bias<true, 64><<<dim3(1024 / 128, 4096 / 64), 256, 0, stream>>>(
        X2, woutT, b_out, out, 4096, 1024, 1024);
}

// Round 12
// 217.260 us; speedup vs baseline: 1.0598x; 1.0598x over previous
//
#include <hip/hip_runtime.h>
#include <hip/hip_bf16.h>
#include <cstdint>

typedef __bf16 bf16x8 __attribute__((ext_vector_type(8)));
typedef float  f32x4  __attribute__((ext_vector_type(4)));

#define S_LEN 4096
#define D_EMB 1024
#define N3    3072
#define HDIM  64

__device__ __forceinline__ unsigned short f2bf(float f) {
    union { unsigned int i; float f; } v; v.f = f;
    unsigned int i = v.i;
    return (unsigned short)((i + 0x7FFFu + ((i >> 16) & 1u)) >> 16);
}

// raw 2^x (1 ulp, same HW op __expf uses after its own log2e mul)
__device__ __forceinline__ float vexp2(float x) {
    float r; asm("v_exp_f32 %0, %1" : "=v"(r) : "v"(x)); return r;
}

// pack 2 fp32 -> 2 bf16, round-half-up: (u+0x8000)>>16. Max error 0.5 ulp.
__device__ __forceinline__ unsigned int pkbf(float lo, float hi) {
    union { float f; unsigned int u; } a, b; a.f = lo; b.f = hi;
    return ((a.u + 0x8000u) >> 16) | ((b.u + 0x8000u) & 0xFFFF0000u);
}

// async global->LDS, 16B/lane; LDS dest must be wave-uniform base + lane*16.
__device__ __forceinline__ void async16(const void* g, void* l) {
    __builtin_amdgcn_global_load_lds(
        (const __attribute__((address_space(1))) unsigned int*)g,
        (__attribute__((address_space(3))) unsigned int*)l,
        16, 0, 0);
}

// fp32 -> bf16 bulk convert, 8 elems/thread
__global__ void convert_f32_bf16(const float* __restrict__ src,
                                 unsigned short* __restrict__ dst, int n8) {
    const int i = blockIdx.x * blockDim.x + threadIdx.x;
    if (i >= n8) return;
    float4 f0 = *(const float4*)&src[i * 8];
    float4 f1 = *(const float4*)&src[i * 8 + 4];
    union { uint4 q; unsigned short s[8]; } o;
    o.s[0]=f2bf(f0.x); o.s[1]=f2bf(f0.y); o.s[2]=f2bf(f0.z); o.s[3]=f2bf(f0.w);
    o.s[4]=f2bf(f1.x); o.s[5]=f2bf(f1.y); o.s[6]=f2bf(f1.z); o.s[7]=f2bf(f1.w);
    *(uint4*)&dst[i * 8] = o.q;
}

// dst[c][r] = bf16(src[r*ld + c0 + c]);  src fp32, dst bf16 [C_][R]
__global__ void transpose_f32_to_bf16(const float* __restrict__ src,
                                      unsigned short* __restrict__ dst,
                                      int R, int ld, int c0) {
    __shared__ float tile[32][33];
    const int tx = threadIdx.x, ty = threadIdx.y;
    const int r0 = blockIdx.y * 32, cc0 = blockIdx.x * 32;
    for (int i = 0; i < 32; i += 8)
        tile[ty + i][tx] = src[(size_t)(r0 + ty + i) * ld + c0 + cc0 + tx];
    __syncthreads();
    for (int i = 0; i < 32; i += 8)
        dst[(size_t)(cc0 + ty + i) * R + r0 + tx] = f2bf(tile[tx][ty + i]);
}

// C[M,N] = A[M,K] @ BT[N,K]^T + bias[N]. A,BT bf16; bias fp32; fp32 accum.
// BM x 128 tile, BK=32, 4 waves. r8 champion form: 2-buffer pipelined
// staging — stage(t+1) before compute(t); the __syncthreads vmcnt(0) drain
// lands after the compute phase. (r9 counted-vmcnt 3-buf: negative. r11
// 256^2: negative — fill/co-residency loss beat per-wave amortization.)
// Round 12: V_SPLIT fuses the qkv->Vt transpose into the epilogue. Blocks
// with n0 >= 2048 (the V columns) write Vt[col-2048][row] directly instead
// of qkv[row][col]; every 64B line of Vt is fully written by one wave's
// store loop (L2 write-combines), same store count, same f2bf — bit-exact.
// Kills the transpose_bf16 kernel (17 MB traffic + launch + serial dep).
template <bool OUT_F32, int BM, bool V_SPLIT>
__global__ __launch_bounds__(256) void gemm_bt_bias(
    const unsigned short* __restrict__ A,
    const unsigned short* __restrict__ BT,
    const float* __restrict__ bias,
    void* __restrict__ Cp,
    unsigned short* __restrict__ Vt,
    int M, int N, int K)
{
    constexpr int MI = BM / 32;   // 16-row fragments per wave (4 or 2)
    __shared__ __align__(16) unsigned short As[2][BM * 32];
    __shared__ __align__(16) unsigned short Bs[2][128 * 32];
    const int tid  = threadIdx.x;
    const int wave = tid >> 6, lane = tid & 63;
    const int q4 = lane >> 4, l16 = lane & 15;
    const int m0 = blockIdx.y * BM, n0 = blockIdx.x * 128;
    const int wm = (wave >> 1) * (BM / 2), wn = (wave & 1) * 64;

    f32x4 acc[MI][4] = {};

    const int srowA = wave * (BM / 4) + (lane >> 2);   // + i*16
    const int srowB = wave * 32 + (lane >> 2);         // + i*16
    const int scol  = (lane & 3) * 8;

    auto stage = [&](int buf, int k0) {
#pragma unroll
        for (int i = 0; i < BM / 64; ++i) {
            const int r = srowA + i * 16;
            async16(A + (size_t)(m0 + r) * K + k0 + scol,
                    &As[buf][(wave * (BM / 4) + i * 16) * 32 + lane * 8]);
        }
#pragma unroll
        for (int i = 0; i < 2; ++i) {
            const int r = srowB + i * 16;
            async16(BT + (size_t)(n0 + r) * K + k0 + scol,
                    &Bs[buf][(wave * 32 + i * 16) * 32 + lane * 8]);
        }
    };

    const int nt = K / 32;
    stage(0, 0);
    __syncthreads();            // vmcnt(0) drain + barrier: tile 0 ready

    int cur = 0;
    for (int t = 0; t < nt; ++t) {
        if (t + 1 < nt) stage(cur ^ 1, (t + 1) * 32);   // issue next tile now

        bf16x8 af[MI], bfr[4];
#pragma unroll
        for (int mi = 0; mi < MI; ++mi)
            af[mi] = *(const bf16x8*)&As[cur][(wm + mi * 16 + l16) * 32 + q4 * 8];
#pragma unroll
        for (int ni = 0; ni < 4; ++ni)
            bfr[ni] = *(const bf16x8*)&Bs[cur][(wn + ni * 16 + l16) * 32 + q4 * 8];
#pragma unroll
        for (int mi = 0; mi < MI; ++mi)
#pragma unroll
            for (int ni = 0; ni < 4; ++ni)
                acc[mi][ni] = __builtin_amdgcn_mfma_f32_16x16x32_bf16(
                    af[mi], bfr[ni], acc[mi][ni], 0, 0, 0);

        __syncthreads();        // drains stage(t+1); protects buf reuse
        cur ^= 1;
    }

    // epilogue: C/D layout col = lane&15, row = (lane>>4)*4 + reg
    const bool vblk = V_SPLIT && (n0 >= 2 * D_EMB);
#pragma unroll
    for (int ni = 0; ni < 4; ++ni) {
        const int col = n0 + wn + ni * 16 + l16;
        const float bv = bias[col];
#pragma unroll
        for (int mi = 0; mi < MI; ++mi) {
            const int row = m0 + wm + mi * 16 + q4 * 4;
#pragma unroll
            for (int r = 0; r < 4; ++r) {
                const float val = acc[mi][ni][r] + bv;
                if constexpr (OUT_F32) {
                    ((float*)Cp)[(size_t)(row + r) * N + col] = val;
                } else {
                    if (V_SPLIT && vblk)
                        Vt[(size_t)(col - 2 * D_EMB) * S_LEN + row + r] = f2bf(val);
                    else
                        ((unsigned short*)Cp)[(size_t)(row + r) * N + col] = f2bf(val);
                }
            }
        }
    }
}

// Causal flash attention, static-max softmax (scores ~N(0,0.17), |s|<~4).
// qkv [S][3072] bf16 (V columns unused), Vt [1024][S] bf16, X2 [S][1024].
// Grid (64,16); q-tile remapped per head-group so the 4 co-resident blocks
// per CU have complementary causal work (130 kv-tiles per CU, balanced).
// EXACT round-10 champion (81.2 us): swapped QK^T -> packed uint2 P-writes,
// T14 register prefetch, vexp2 pre-folded scale, pair-pack bf16, mask
// unswitched to diagonal tile. Constraints: VGPR<=64, LDS 27.6K, K/V
// LDS-staged, no setprio, no per-wave q doubling.
#define LDP 72   // padded row stride (shorts): 144 B breaks the 128 B conflict
__global__ __launch_bounds__(256) void attn_flash(
    const unsigned short* __restrict__ qkv,
    const unsigned short* __restrict__ Vt,
    unsigned short* __restrict__ X2)
{
    __shared__ __align__(16) unsigned short Ks[64 * LDP];      // [kv][d]
    __shared__ __align__(16) unsigned short Vs[64 * LDP];      // [d][kv]
    __shared__ __align__(16) unsigned short Ps[4 * 16 * LDP];  // per-wave [16 q][64 kv]
    const int tid  = threadIdx.x;
    const int wave = tid >> 6, lane = tid & 63;
    const int q4 = lane >> 4, l16 = lane & 15;
    const int h  = blockIdx.y;

    // balanced q-tile mapping: head-group k gets {x, 63-x, x+16, 47-x}
    const int x = blockIdx.x, hg = blockIdx.y >> 2;
    int qt;
    if      (hg == 0) qt = x;
    else if (hg == 1) qt = 63 - x;
    else if (hg == 2) qt = (x + 16) & 63;
    else              qt = (47 - x) & 63;
    const int q0 = qt * 64;

    // Q frags (A/B layouts match: idx = lane&15, k = quad*8+j)
    bf16x8 aq[2];
    {
        const unsigned short* qp =
            qkv + (size_t)(q0 + wave * 16 + l16) * N3 + h * HDIM + q4 * 8;
        aq[0] = *(const bf16x8*)(qp);
        aq[1] = *(const bf16x8*)(qp + 32);
    }

    float l_part = 0.f;
    f32x4 o[4] = {};

    const int rr = tid >> 3;        // 0..31
    const int cc = (tid & 7) * 8;   // 0..56
    const int ntile = qt + 1;
    const int grow = q0 + wave * 16 + l16;   // this lane's q row (swapped layout)

    const float SCL = 0.18033688f;  // 0.125 * log2(e)

    // prefetch tile 0 into registers
    uint4 kv_a, kv_b, vt_a, vt_b;
    {
        kv_a = *(const uint4*)&qkv[(size_t)(rr)      * N3 + D_EMB + h * HDIM + cc];
        kv_b = *(const uint4*)&qkv[(size_t)(32 + rr) * N3 + D_EMB + h * HDIM + cc];
        vt_a = *(const uint4*)&Vt [(size_t)(h * HDIM + rr)      * S_LEN + cc];
        vt_b = *(const uint4*)&Vt [(size_t)(h * HDIM + 32 + rr) * S_LEN + cc];
    }

    for (int t = 0; t < ntile; ++t) {
        const int kv0 = t * 64;
        __syncthreads();   // prior tile's LDS reads complete
        *(uint4*)&Ks[rr * LDP + cc]        = kv_a;
        *(uint4*)&Ks[(32 + rr) * LDP + cc] = kv_b;
        *(uint4*)&Vs[rr * LDP + cc]        = vt_a;
        *(uint4*)&Vs[(32 + rr) * LDP + cc] = vt_b;
        // issue next tile's loads now; compute below hides their latency
        if (t + 1 < ntile) {
            const int kn = kv0 + 64;
            kv_a = *(const uint4*)&qkv[(size_t)(kn + rr)      * N3 + D_EMB + h * HDIM + cc];
            kv_b = *(const uint4*)&qkv[(size_t)(kn + 32 + rr) * N3 + D_EMB + h * HDIM + cc];
            vt_a = *(const uint4*)&Vt [(size_t)(h * HDIM + rr)      * S_LEN + kn + cc];
            vt_b = *(const uint4*)&Vt [(size_t)(h * HDIM + 32 + rr) * S_LEN + kn + cc];
        }
        __syncthreads();

        // S^T = K Q^T (A = K rows (m=kv), B = Q (n=q))
        f32x4 sacc[4] = {};
#pragma unroll
        for (int kk = 0; kk < 2; ++kk)
#pragma unroll
            for (int nt = 0; nt < 4; ++nt) {
                bf16x8 kf = *(const bf16x8*)&Ks[(nt * 16 + l16) * LDP + kk * 32 + q4 * 8];
                sacc[nt] = __builtin_amdgcn_mfma_f32_16x16x32_bf16(
                    kf, aq[kk], sacc[nt], 0, 0, 0);
            }

        // softmax-lite; mask only on the diagonal tile
        if (t != ntile - 1) {
#pragma unroll
            for (int nt = 0; nt < 4; ++nt) {
                float e0 = vexp2(sacc[nt][0] * SCL);
                float e1 = vexp2(sacc[nt][1] * SCL);
                float e2 = vexp2(sacc[nt][2] * SCL);
                float e3 = vexp2(sacc[nt][3] * SCL);
                l_part += e0; l_part += e1; l_part += e2; l_part += e3;
                uint2 pk;
                pk.x = pkbf(e0, e1);
                pk.y = pkbf(e2, e3);
                *(uint2*)&Ps[wave * 16 * LDP + l16 * LDP + nt * 16 + q4 * 4] = pk;
            }
        } else {
#pragma unroll
            for (int nt = 0; nt < 4; ++nt) {
                float e[4];
#pragma unroll
                for (int r = 0; r < 4; ++r) {
                    e[r] = vexp2(sacc[nt][r] * SCL);
                    if (kv0 + nt * 16 + q4 * 4 + r > grow) e[r] = 0.f;
                    l_part += e[r];
                }
                uint2 pk;
                pk.x = pkbf(e[0], e[1]);
                pk.y = pkbf(e[2], e[3]);
                *(uint2*)&Ps[wave * 16 * LDP + l16 * LDP + nt * 16 + q4 * 4] = pk;
            }
        }
        // per-wave LDS roundtrip: only need this wave's writes visible
        __asm__ volatile("s_waitcnt lgkmcnt(0)" ::: "memory");

        // O += P V
#pragma unroll
        for (int kk = 0; kk < 2; ++kk) {
            bf16x8 pa = *(const bf16x8*)&Ps[wave * 16 * LDP + l16 * LDP + kk * 32 + q4 * 8];
#pragma unroll
            for (int dt = 0; dt < 4; ++dt) {
                bf16x8 vb = *(const bf16x8*)&Vs[(dt * 16 + l16) * LDP + kk * 32 + q4 * 8];
                o[dt] = __builtin_amdgcn_mfma_f32_16x16x32_bf16(
                    pa, vb, o[dt], 0, 0, 0);
            }
        }
    }

    // row-sum: lane holds partial for q = l16; reduce across the 4 quads
    float l = l_part;
    l += __shfl_xor(l, 16);
    l += __shfl_xor(l, 32);
    float linv[4];
#pragma unroll
    for (int r = 0; r < 4; ++r)
        linv[r] = 1.f / __shfl(l, q4 * 4 + r);

#pragma unroll
    for (int dt = 0; dt < 4; ++dt)
#pragma unroll
        for (int r = 0; r < 4; ++r) {
            const int row = q0 + wave * 16 + q4 * 4 + r;
            X2[(size_t)row * D_EMB + h * HDIM + dt * 16 + l16] =
                f2bf(o[dt][r] * linv[r]);
        }
}

extern "C" void kernel_launch(void* const* d_in, const int* in_sizes, int n_in,
                              void* d_out, int out_size, void* d_ws, size_t ws_size,
                              hipStream_t stream) {
    const float* x     = (const float*)d_in[0];   // [4096][1024] fp32
    const float* w_qkv = (const float*)d_in[1];   // [1024][3072] fp32
    const float* b_qkv = (const float*)d_in[2];   // [3072] fp32
    const float* w_out = (const float*)d_in[3];   // [1024][1024] fp32
    const float* b_out = (const float*)d_in[4];   // [1024] fp32
    float* out = (float*)d_out;                   // [4096][1024] fp32

    char* ws = (char*)d_ws;
    unsigned short* qkv   = (unsigned short*)(ws);              // 24 MB
    unsigned short* wqkvT = (unsigned short*)(ws + 25165824);   //  6 MB
    unsigned short* woutT = (unsigned short*)(ws + 31457280);   //  2 MB
    unsigned short* Vt    = (unsigned short*)(ws + 33554432);   //  8 MB
    unsigned short* X2    = (unsigned short*)(ws + 41943040);   //  8 MB
    unsigned short* Xb    = X2;  // aliased: Xb consumed by GEMM1 before attn writes X2

    // x -> bf16
    convert_f32_bf16<<<(4096 * 1024 / 8 + 255) / 256, 256, 0, stream>>>(
        x, Xb, 4096 * 1024 / 8);

    // weight transposes + fp32->bf16 -> BT layout
    transpose_f32_to_bf16<<<dim3(3072 / 32, 1024 / 32), dim3(32, 8), 0, stream>>>(
        w_qkv, wqkvT, 1024, 3072, 0);
    transpose_f32_to_bf16<<<dim3(1024 / 32, 1024 / 32), dim3(32, 8), 0, stream>>>(
        w_out, woutT, 1024, 1024, 0);

    // qkv = Xb @ w_qkv + b_qkv; Q/K -> qkv rows, V -> Vt transposed (fused)
    gemm_bt_bias<false, 128, true><<<dim3(3072 / 128, 4096 / 128), 256, 0, stream>>>(
        Xb, wqkvT, b_qkv, qkv, Vt, 4096, 3072, 1024);

    // causal flash attention -> X2 [S][1024] bf16
    attn_flash<<<dim3(64, 16), 256, 0, stream>>>(qkv, Vt, X2);

    // out = X2 @ w_out + b_out  (fp32 out), 64x128 tiles, pipelined (r8)
    gemm_bt_bias<true, 64, false><<<dim3(1024 / 128, 4096 / 64), 256, 0, stream>>>(
        X2, woutT, b_out, out, nullptr, 4096, 1024, 1024);
}

// Round 13
// 211.333 us; speedup vs baseline: 1.0896x; 1.0280x over previous
//
#include <hip/hip_runtime.h>
#include <hip/hip_bf16.h>
#include <cstdint>

typedef __bf16 bf16x8 __attribute__((ext_vector_type(8)));
typedef float  f32x4  __attribute__((ext_vector_type(4)));

#define S_LEN 4096
#define D_EMB 1024
#define N3    3072
#define HDIM  64

__device__ __forceinline__ unsigned short f2bf(float f) {
    union { unsigned int i; float f; } v; v.f = f;
    unsigned int i = v.i;
    return (unsigned short)((i + 0x7FFFu + ((i >> 16) & 1u)) >> 16);
}

// raw 2^x (1 ulp, same HW op __expf uses after its own log2e mul)
__device__ __forceinline__ float vexp2(float x) {
    float r; asm("v_exp_f32 %0, %1" : "=v"(r) : "v"(x)); return r;
}

// pack 2 fp32 -> 2 bf16, round-half-up: (u+0x8000)>>16. Max error 0.5 ulp.
__device__ __forceinline__ unsigned int pkbf(float lo, float hi) {
    union { float f; unsigned int u; } a, b; a.f = lo; b.f = hi;
    return ((a.u + 0x8000u) >> 16) | ((b.u + 0x8000u) & 0xFFFF0000u);
}

// async global->LDS, 16B/lane; LDS dest must be wave-uniform base + lane*16.
__device__ __forceinline__ void async16(const void* g, void* l) {
    __builtin_amdgcn_global_load_lds(
        (const __attribute__((address_space(1))) unsigned int*)g,
        (__attribute__((address_space(3))) unsigned int*)l,
        16, 0, 0);
}

// fp32 -> bf16 bulk convert, 8 elems/thread
__global__ void convert_f32_bf16(const float* __restrict__ src,
                                 unsigned short* __restrict__ dst, int n8) {
    const int i = blockIdx.x * blockDim.x + threadIdx.x;
    if (i >= n8) return;
    float4 f0 = *(const float4*)&src[i * 8];
    float4 f1 = *(const float4*)&src[i * 8 + 4];
    union { uint4 q; unsigned short s[8]; } o;
    o.s[0]=f2bf(f0.x); o.s[1]=f2bf(f0.y); o.s[2]=f2bf(f0.z); o.s[3]=f2bf(f0.w);
    o.s[4]=f2bf(f1.x); o.s[5]=f2bf(f1.y); o.s[6]=f2bf(f1.z); o.s[7]=f2bf(f1.w);
    *(uint4*)&dst[i * 8] = o.q;
}

// Round 13: both weight transposes in ONE launch (independent, identical
// 1024-source-row geometry). Blocks x<96: w_qkv [1024][3072] -> wqkvT;
// x>=96: w_out [1024][1024] -> woutT. Body identical to the verified
// transpose_f32_to_bf16 (R=1024, c0=0). Saves a dispatch + launch gap.
__global__ void transpose_weights(const float* __restrict__ wq,
                                  const float* __restrict__ wo,
                                  unsigned short* __restrict__ dq,
                                  unsigned short* __restrict__ dwo) {
    __shared__ float tile[32][33];
    const int tx = threadIdx.x, ty = threadIdx.y;
    const int bx = blockIdx.x;
    const float* src;
    unsigned short* dst;
    int ld, cc0;
    if (bx < 96) { src = wq; dst = dq;  ld = 3072; cc0 = bx * 32; }
    else         { src = wo; dst = dwo; ld = 1024; cc0 = (bx - 96) * 32; }
    const int r0 = blockIdx.y * 32;
    for (int i = 0; i < 32; i += 8)
        tile[ty + i][tx] = src[(size_t)(r0 + ty + i) * ld + cc0 + tx];
    __syncthreads();
    for (int i = 0; i < 32; i += 8)
        dst[(size_t)(cc0 + ty + i) * 1024 + r0 + tx] = f2bf(tile[tx][ty + i]);
}

// dst[c][r] = src[r*ld + c0 + c];  bf16 -> bf16, dst [C_][R]
__global__ void transpose_bf16(const unsigned short* __restrict__ src,
                               unsigned short* __restrict__ dst,
                               int R, int ld, int c0) {
    __shared__ unsigned short tile[32][33];
    const int tx = threadIdx.x, ty = threadIdx.y;
    const int r0 = blockIdx.y * 32, cc0 = blockIdx.x * 32;
    for (int i = 0; i < 32; i += 8)
        tile[ty + i][tx] = src[(size_t)(r0 + ty + i) * ld + c0 + cc0 + tx];
    __syncthreads();
    for (int i = 0; i < 32; i += 8)
        dst[(size_t)(cc0 + ty + i) * R + r0 + tx] = tile[tx][ty + i];
}

// C[M,N] = A[M,K] @ BT[N,K]^T + bias[N]. A,BT bf16; bias fp32; fp32 accum.
// BM x 128 tile, BK=32, 4 waves. r8 champion form: 2-buffer pipelined
// staging — stage(t+1) before compute(t); the __syncthreads vmcnt(0) drain
// lands after the compute phase. Session verdicts: BK=64 null (r7);
// 3-buf counted-vmcnt negative (r9); 256^2 negative at K=1024/0.75-fill
// (r11); V->Vt scattered-store fusion negative (r12 — store coalescing
// matters as much as load coalescing).
template <bool OUT_F32, int BM>
__global__ __launch_bounds__(256) void gemm_bt_bias(
    const unsigned short* __restrict__ A,
    const unsigned short* __restrict__ BT,
    const float* __restrict__ bias,
    void* __restrict__ Cp,
    int M, int N, int K)
{
    constexpr int MI = BM / 32;   // 16-row fragments per wave (4 or 2)
    __shared__ __align__(16) unsigned short As[2][BM * 32];
    __shared__ __align__(16) unsigned short Bs[2][128 * 32];
    const int tid  = threadIdx.x;
    const int wave = tid >> 6, lane = tid & 63;
    const int q4 = lane >> 4, l16 = lane & 15;
    const int m0 = blockIdx.y * BM, n0 = blockIdx.x * 128;
    const int wm = (wave >> 1) * (BM / 2), wn = (wave & 1) * 64;

    f32x4 acc[MI][4] = {};

    const int srowA = wave * (BM / 4) + (lane >> 2);   // + i*16
    const int srowB = wave * 32 + (lane >> 2);         // + i*16
    const int scol  = (lane & 3) * 8;

    auto stage = [&](int buf, int k0) {
#pragma unroll
        for (int i = 0; i < BM / 64; ++i) {
            const int r = srowA + i * 16;
            async16(A + (size_t)(m0 + r) * K + k0 + scol,
                    &As[buf][(wave * (BM / 4) + i * 16) * 32 + lane * 8]);
        }
#pragma unroll
        for (int i = 0; i < 2; ++i) {
            const int r = srowB + i * 16;
            async16(BT + (size_t)(n0 + r) * K + k0 + scol,
                    &Bs[buf][(wave * 32 + i * 16) * 32 + lane * 8]);
        }
    };

    const int nt = K / 32;
    stage(0, 0);
    __syncthreads();            // vmcnt(0) drain + barrier: tile 0 ready

    int cur = 0;
    for (int t = 0; t < nt; ++t) {
        if (t + 1 < nt) stage(cur ^ 1, (t + 1) * 32);   // issue next tile now

        bf16x8 af[MI], bfr[4];
#pragma unroll
        for (int mi = 0; mi < MI; ++mi)
            af[mi] = *(const bf16x8*)&As[cur][(wm + mi * 16 + l16) * 32 + q4 * 8];
#pragma unroll
        for (int ni = 0; ni < 4; ++ni)
            bfr[ni] = *(const bf16x8*)&Bs[cur][(wn + ni * 16 + l16) * 32 + q4 * 8];
#pragma unroll
        for (int mi = 0; mi < MI; ++mi)
#pragma unroll
            for (int ni = 0; ni < 4; ++ni)
                acc[mi][ni] = __builtin_amdgcn_mfma_f32_16x16x32_bf16(
                    af[mi], bfr[ni], acc[mi][ni], 0, 0, 0);

        __syncthreads();        // drains stage(t+1); protects buf reuse
        cur ^= 1;
    }

    // epilogue: C/D layout col = lane&15, row = (lane>>4)*4 + reg
#pragma unroll
    for (int ni = 0; ni < 4; ++ni) {
        const int col = n0 + wn + ni * 16 + l16;
        const float bv = bias[col];
#pragma unroll
        for (int mi = 0; mi < MI; ++mi) {
            const int row = m0 + wm + mi * 16 + q4 * 4;
#pragma unroll
            for (int r = 0; r < 4; ++r) {
                const float val = acc[mi][ni][r] + bv;
                if constexpr (OUT_F32)
                    ((float*)Cp)[(size_t)(row + r) * N + col] = val;
                else
                    ((unsigned short*)Cp)[(size_t)(row + r) * N + col] = f2bf(val);
            }
        }
    }
}

// Causal flash attention, static-max softmax (scores ~N(0,0.17), |s|<~4).
// qkv [S][3072] bf16, Vt [1024][S] bf16, X2 [S][1024] bf16.
// Grid (64,16); q-tile remapped per head-group so the 4 co-resident blocks
// per CU have complementary causal work (130 kv-tiles per CU, balanced).
// EXACT round-10 champion (81.2 us): swapped QK^T -> packed uint2 P-writes,
// T14 register prefetch, vexp2 pre-folded scale, pair-pack bf16, mask
// unswitched to diagonal tile. Constraints: VGPR<=64, LDS 27.6K, K/V
// LDS-staged, no setprio, no per-wave q doubling.
#define LDP 72   // padded row stride (shorts): 144 B breaks the 128 B conflict
__global__ __launch_bounds__(256) void attn_flash(
    const unsigned short* __restrict__ qkv,
    const unsigned short* __restrict__ Vt,
    unsigned short* __restrict__ X2)
{
    __shared__ __align__(16) unsigned short Ks[64 * LDP];      // [kv][d]
    __shared__ __align__(16) unsigned short Vs[64 * LDP];      // [d][kv]
    __shared__ __align__(16) unsigned short Ps[4 * 16 * LDP];  // per-wave [16 q][64 kv]
    const int tid  = threadIdx.x;
    const int wave = tid >> 6, lane = tid & 63;
    const int q4 = lane >> 4, l16 = lane & 15;
    const int h  = blockIdx.y;

    // balanced q-tile mapping: head-group k gets {x, 63-x, x+16, 47-x}
    const int x = blockIdx.x, hg = blockIdx.y >> 2;
    int qt;
    if      (hg == 0) qt = x;
    else if (hg == 1) qt = 63 - x;
    else if (hg == 2) qt = (x + 16) & 63;
    else              qt = (47 - x) & 63;
    const int q0 = qt * 64;

    // Q frags (A/B layouts match: idx = lane&15, k = quad*8+j)
    bf16x8 aq[2];
    {
        const unsigned short* qp =
            qkv + (size_t)(q0 + wave * 16 + l16) * N3 + h * HDIM + q4 * 8;
        aq[0] = *(const bf16x8*)(qp);
        aq[1] = *(const bf16x8*)(qp + 32);
    }

    float l_part = 0.f;
    f32x4 o[4] = {};

    const int rr = tid >> 3;        // 0..31
    const int cc = (tid & 7) * 8;   // 0..56
    const int ntile = qt + 1;
    const int grow = q0 + wave * 16 + l16;   // this lane's q row (swapped layout)

    const float SCL = 0.18033688f;  // 0.125 * log2(e)

    // prefetch tile 0 into registers
    uint4 kv_a, kv_b, vt_a, vt_b;
    {
        kv_a = *(const uint4*)&qkv[(size_t)(rr)      * N3 + D_EMB + h * HDIM + cc];
        kv_b = *(const uint4*)&qkv[(size_t)(32 + rr) * N3 + D_EMB + h * HDIM + cc];
        vt_a = *(const uint4*)&Vt [(size_t)(h * HDIM + rr)      * S_LEN + cc];
        vt_b = *(const uint4*)&Vt [(size_t)(h * HDIM + 32 + rr) * S_LEN + cc];
    }

    for (int t = 0; t < ntile; ++t) {
        const int kv0 = t * 64;
        __syncthreads();   // prior tile's LDS reads complete
        *(uint4*)&Ks[rr * LDP + cc]        = kv_a;
        *(uint4*)&Ks[(32 + rr) * LDP + cc] = kv_b;
        *(uint4*)&Vs[rr * LDP + cc]        = vt_a;
        *(uint4*)&Vs[(32 + rr) * LDP + cc] = vt_b;
        // issue next tile's loads now; compute below hides their latency
        if (t + 1 < ntile) {
            const int kn = kv0 + 64;
            kv_a = *(const uint4*)&qkv[(size_t)(kn + rr)      * N3 + D_EMB + h * HDIM + cc];
            kv_b = *(const uint4*)&qkv[(size_t)(kn + 32 + rr) * N3 + D_EMB + h * HDIM + cc];
            vt_a = *(const uint4*)&Vt [(size_t)(h * HDIM + rr)      * S_LEN + kn + cc];
            vt_b = *(const uint4*)&Vt [(size_t)(h * HDIM + 32 + rr) * S_LEN + kn + cc];
        }
        __syncthreads();

        // S^T = K Q^T (A = K rows (m=kv), B = Q (n=q))
        f32x4 sacc[4] = {};
#pragma unroll
        for (int kk = 0; kk < 2; ++kk)
#pragma unroll
            for (int nt = 0; nt < 4; ++nt) {
                bf16x8 kf = *(const bf16x8*)&Ks[(nt * 16 + l16) * LDP + kk * 32 + q4 * 8];
                sacc[nt] = __builtin_amdgcn_mfma_f32_16x16x32_bf16(
                    kf, aq[kk], sacc[nt], 0, 0, 0);
            }

        // softmax-lite; mask only on the diagonal tile
        if (t != ntile - 1) {
#pragma unroll
            for (int nt = 0; nt < 4; ++nt) {
                float e0 = vexp2(sacc[nt][0] * SCL);
                float e1 = vexp2(sacc[nt][1] * SCL);
                float e2 = vexp2(sacc[nt][2] * SCL);
                float e3 = vexp2(sacc[nt][3] * SCL);
                l_part += e0; l_part += e1; l_part += e2; l_part += e3;
                uint2 pk;
                pk.x = pkbf(e0, e1);
                pk.y = pkbf(e2, e3);
                *(uint2*)&Ps[wave * 16 * LDP + l16 * LDP + nt * 16 + q4 * 4] = pk;
            }
        } else {
#pragma unroll
            for (int nt = 0; nt < 4; ++nt) {
                float e[4];
#pragma unroll
                for (int r = 0; r < 4; ++r) {
                    e[r] = vexp2(sacc[nt][r] * SCL);
                    if (kv0 + nt * 16 + q4 * 4 + r > grow) e[r] = 0.f;
                    l_part += e[r];
                }
                uint2 pk;
                pk.x = pkbf(e[0], e[1]);
                pk.y = pkbf(e[2], e[3]);
                *(uint2*)&Ps[wave * 16 * LDP + l16 * LDP + nt * 16 + q4 * 4] = pk;
            }
        }
        // per-wave LDS roundtrip: only need this wave's writes visible
        __asm__ volatile("s_waitcnt lgkmcnt(0)" ::: "memory");

        // O += P V
#pragma unroll
        for (int kk = 0; kk < 2; ++kk) {
            bf16x8 pa = *(const bf16x8*)&Ps[wave * 16 * LDP + l16 * LDP + kk * 32 + q4 * 8];
#pragma unroll
            for (int dt = 0; dt < 4; ++dt) {
                bf16x8 vb = *(const bf16x8*)&Vs[(dt * 16 + l16) * LDP + kk * 32 + q4 * 8];
                o[dt] = __builtin_amdgcn_mfma_f32_16x16x32_bf16(
                    pa, vb, o[dt], 0, 0, 0);
            }
        }
    }

    // row-sum: lane holds partial for q = l16; reduce across the 4 quads
    float l = l_part;
    l += __shfl_xor(l, 16);
    l += __shfl_xor(l, 32);
    float linv[4];
#pragma unroll
    for (int r = 0; r < 4; ++r)
        linv[r] = 1.f / __shfl(l, q4 * 4 + r);

#pragma unroll
    for (int dt = 0; dt < 4; ++dt)
#pragma unroll
        for (int r = 0; r < 4; ++r) {
            const int row = q0 + wave * 16 + q4 * 4 + r;
            X2[(size_t)row * D_EMB + h * HDIM + dt * 16 + l16] =
                f2bf(o[dt][r] * linv[r]);
        }
}

extern "C" void kernel_launch(void* const* d_in, const int* in_sizes, int n_in,
                              void* d_out, int out_size, void* d_ws, size_t ws_size,
                              hipStream_t stream) {
    const float* x     = (const float*)d_in[0];   // [4096][1024] fp32
    const float* w_qkv = (const float*)d_in[1];   // [1024][3072] fp32
    const float* b_qkv = (const float*)d_in[2];   // [3072] fp32
    const float* w_out = (const float*)d_in[3];   // [1024][1024] fp32
    const float* b_out = (const float*)d_in[4];   // [1024] fp32
    float* out = (float*)d_out;                   // [4096][1024] fp32

    char* ws = (char*)d_ws;
    unsigned short* qkv   = (unsigned short*)(ws);              // 24 MB
    unsigned short* wqkvT = (unsigned short*)(ws + 25165824);   //  6 MB
    unsigned short* woutT = (unsigned short*)(ws + 31457280);   //  2 MB
    unsigned short* Vt    = (unsigned short*)(ws + 33554432);   //  8 MB
    unsigned short* X2    = (unsigned short*)(ws + 41943040);   //  8 MB
    unsigned short* Xb    = X2;  // aliased: Xb consumed by GEMM1 before attn writes X2

    // x -> bf16
    convert_f32_bf16<<<(4096 * 1024 / 8 + 255) / 256, 256, 0, stream>>>(
        x, Xb, 4096 * 1024 / 8);

    // both weight transposes, one launch (r13)
    transpose_weights<<<dim3(128, 32), dim3(32, 8), 0, stream>>>(
        w_qkv, w_out, wqkvT, woutT);

    // qkv = Xb @ w_qkv + b_qkv  (bf16 out), 128x128 tiles, pipelined (r8)
    gemm_bt_bias<false, 128><<<dim3(3072 / 128, 4096 / 128), 256, 0, stream>>>(
        Xb, wqkvT, b_qkv, qkv, 4096, 3072, 1024);

    // Vt[h*64+d][s] = V[s][h*64+d]
    transpose_bf16<<<dim3(1024 / 32, 4096 / 32), dim3(32, 8), 0, stream>>>(
        qkv, Vt, 4096, 3072, 2048);

    // causal flash attention -> X2 [S][1024] bf16
    attn_flash<<<dim3(64, 16), 256, 0, stream>>>(qkv, Vt, X2);

    // out = X2 @ w_out + b_out  (fp32 out), 64x128 tiles, pipelined (r8)
    gemm_bt_bias<true, 64><<<dim3(1024 / 128, 4096 / 64), 256, 0, stream>>>(
        X2, woutT, b_out, out, 4096, 1024, 1024);
}

// Round 14
// 211.202 us; speedup vs baseline: 1.0902x; 1.0006x over previous
//
#include <hip/hip_runtime.h>
#include <hip/hip_bf16.h>
#include <cstdint>

typedef __bf16 bf16x8 __attribute__((ext_vector_type(8)));
typedef float  f32x4  __attribute__((ext_vector_type(4)));

#define S_LEN 4096
#define D_EMB 1024
#define N3    3072
#define HDIM  64

__device__ __forceinline__ unsigned short f2bf(float f) {
    union { unsigned int i; float f; } v; v.f = f;
    unsigned int i = v.i;
    return (unsigned short)((i + 0x7FFFu + ((i >> 16) & 1u)) >> 16);
}

// raw 2^x (1 ulp, same HW op __expf uses after its own log2e mul)
__device__ __forceinline__ float vexp2(float x) {
    float r; asm("v_exp_f32 %0, %1" : "=v"(r) : "v"(x)); return r;
}

// pack 2 fp32 -> 2 bf16, round-half-up: (u+0x8000)>>16. Max error 0.5 ulp.
__device__ __forceinline__ unsigned int pkbf(float lo, float hi) {
    union { float f; unsigned int u; } a, b; a.f = lo; b.f = hi;
    return ((a.u + 0x8000u) >> 16) | ((b.u + 0x8000u) & 0xFFFF0000u);
}

// async global->LDS, 16B/lane; LDS dest must be wave-uniform base + lane*16.
__device__ __forceinline__ void async16(const void* g, void* l) {
    __builtin_amdgcn_global_load_lds(
        (const __attribute__((address_space(1))) unsigned int*)g,
        (__attribute__((address_space(3))) unsigned int*)l,
        16, 0, 0);
}

// Round 14: single prologue launch. Blocks [0,2048): x fp32->bf16 convert
// (8 elems/thread; grid exactly n8/256 so no bound check). Blocks
// [2048,6144): the r13 merged weight transpose, reindexed bx=b&127,
// by=b>>7, tx=tid&31, ty=tid>>5 (bit-identical thread roles). Saves one
// dispatch + drain/launch gap; both halves are memory-bound and
// co-schedule freely.
__global__ void prologue(const float* __restrict__ x,
                         unsigned short* __restrict__ Xb,
                         const float* __restrict__ wq,
                         const float* __restrict__ wo,
                         unsigned short* __restrict__ dq,
                         unsigned short* __restrict__ dwo) {
    __shared__ float tile[32][33];
    const int b = blockIdx.x;
    if (b < 2048) {
        const int i = b * 256 + threadIdx.x;   // i < 524288 = 4096*1024/8
        float4 f0 = *(const float4*)&x[i * 8];
        float4 f1 = *(const float4*)&x[i * 8 + 4];
        union { uint4 q; unsigned short s[8]; } o;
        o.s[0]=f2bf(f0.x); o.s[1]=f2bf(f0.y); o.s[2]=f2bf(f0.z); o.s[3]=f2bf(f0.w);
        o.s[4]=f2bf(f1.x); o.s[5]=f2bf(f1.y); o.s[6]=f2bf(f1.z); o.s[7]=f2bf(f1.w);
        *(uint4*)&Xb[i * 8] = o.q;
    } else {
        const int bb = b - 2048;
        const int bx = bb & 127, by = bb >> 7;         // 128 x 32 sub-grid
        const int tx = threadIdx.x & 31, ty = threadIdx.x >> 5;
        const float* src;
        unsigned short* dst;
        int ld, cc0;
        if (bx < 96) { src = wq; dst = dq;  ld = 3072; cc0 = bx * 32; }
        else         { src = wo; dst = dwo; ld = 1024; cc0 = (bx - 96) * 32; }
        const int r0 = by * 32;
        for (int i = 0; i < 32; i += 8)
            tile[ty + i][tx] = src[(size_t)(r0 + ty + i) * ld + cc0 + tx];
        __syncthreads();
        for (int i = 0; i < 32; i += 8)
            dst[(size_t)(cc0 + ty + i) * 1024 + r0 + tx] = f2bf(tile[tx][ty + i]);
    }
}

// dst[c][r] = src[r*ld + c0 + c];  bf16 -> bf16, dst [C_][R]
__global__ void transpose_bf16(const unsigned short* __restrict__ src,
                               unsigned short* __restrict__ dst,
                               int R, int ld, int c0) {
    __shared__ unsigned short tile[32][33];
    const int tx = threadIdx.x, ty = threadIdx.y;
    const int r0 = blockIdx.y * 32, cc0 = blockIdx.x * 32;
    for (int i = 0; i < 32; i += 8)
        tile[ty + i][tx] = src[(size_t)(r0 + ty + i) * ld + c0 + cc0 + tx];
    __syncthreads();
    for (int i = 0; i < 32; i += 8)
        dst[(size_t)(cc0 + ty + i) * R + r0 + tx] = tile[tx][ty + i];
}

// C[M,N] = A[M,K] @ BT[N,K]^T + bias[N]. A,BT bf16; bias fp32; fp32 accum.
// BM x 128 tile, BK=32, 4 waves. r8 champion form: 2-buffer pipelined
// staging — stage(t+1) before compute(t); the __syncthreads vmcnt(0) drain
// lands after the compute phase. Session verdicts: BK=64 null (r7);
// 3-buf counted-vmcnt negative (r9); 256^2 negative at K=1024/0.75-fill
// (r11); V->Vt scattered-store fusion negative (r12 — store coalescing
// matters as much as load coalescing).
template <bool OUT_F32, int BM>
__global__ __launch_bounds__(256) void gemm_bt_bias(
    const unsigned short* __restrict__ A,
    const unsigned short* __restrict__ BT,
    const float* __restrict__ bias,
    void* __restrict__ Cp,
    int M, int N, int K)
{
    constexpr int MI = BM / 32;   // 16-row fragments per wave (4 or 2)
    __shared__ __align__(16) unsigned short As[2][BM * 32];
    __shared__ __align__(16) unsigned short Bs[2][128 * 32];
    const int tid  = threadIdx.x;
    const int wave = tid >> 6, lane = tid & 63;
    const int q4 = lane >> 4, l16 = lane & 15;
    const int m0 = blockIdx.y * BM, n0 = blockIdx.x * 128;
    const int wm = (wave >> 1) * (BM / 2), wn = (wave & 1) * 64;

    f32x4 acc[MI][4] = {};

    const int srowA = wave * (BM / 4) + (lane >> 2);   // + i*16
    const int srowB = wave * 32 + (lane >> 2);         // + i*16
    const int scol  = (lane & 3) * 8;

    auto stage = [&](int buf, int k0) {
#pragma unroll
        for (int i = 0; i < BM / 64; ++i) {
            const int r = srowA + i * 16;
            async16(A + (size_t)(m0 + r) * K + k0 + scol,
                    &As[buf][(wave * (BM / 4) + i * 16) * 32 + lane * 8]);
        }
#pragma unroll
        for (int i = 0; i < 2; ++i) {
            const int r = srowB + i * 16;
            async16(BT + (size_t)(n0 + r) * K + k0 + scol,
                    &Bs[buf][(wave * 32 + i * 16) * 32 + lane * 8]);
        }
    };

    const int nt = K / 32;
    stage(0, 0);
    __syncthreads();            // vmcnt(0) drain + barrier: tile 0 ready

    int cur = 0;
    for (int t = 0; t < nt; ++t) {
        if (t + 1 < nt) stage(cur ^ 1, (t + 1) * 32);   // issue next tile now

        bf16x8 af[MI], bfr[4];
#pragma unroll
        for (int mi = 0; mi < MI; ++mi)
            af[mi] = *(const bf16x8*)&As[cur][(wm + mi * 16 + l16) * 32 + q4 * 8];
#pragma unroll
        for (int ni = 0; ni < 4; ++ni)
            bfr[ni] = *(const bf16x8*)&Bs[cur][(wn + ni * 16 + l16) * 32 + q4 * 8];
#pragma unroll
        for (int mi = 0; mi < MI; ++mi)
#pragma unroll
            for (int ni = 0; ni < 4; ++ni)
                acc[mi][ni] = __builtin_amdgcn_mfma_f32_16x16x32_bf16(
                    af[mi], bfr[ni], acc[mi][ni], 0, 0, 0);

        __syncthreads();        // drains stage(t+1); protects buf reuse
        cur ^= 1;
    }

    // epilogue: C/D layout col = lane&15, row = (lane>>4)*4 + reg
#pragma unroll
    for (int ni = 0; ni < 4; ++ni) {
        const int col = n0 + wn + ni * 16 + l16;
        const float bv = bias[col];
#pragma unroll
        for (int mi = 0; mi < MI; ++mi) {
            const int row = m0 + wm + mi * 16 + q4 * 4;
#pragma unroll
            for (int r = 0; r < 4; ++r) {
                const float val = acc[mi][ni][r] + bv;
                if constexpr (OUT_F32)
                    ((float*)Cp)[(size_t)(row + r) * N + col] = val;
                else
                    ((unsigned short*)Cp)[(size_t)(row + r) * N + col] = f2bf(val);
            }
        }
    }
}

// Causal flash attention, static-max softmax (scores ~N(0,0.17), |s|<~4).
// qkv [S][3072] bf16, Vt [1024][S] bf16, X2 [S][1024] bf16.
// Grid (64,16); q-tile remapped per head-group so the 4 co-resident blocks
// per CU have complementary causal work (130 kv-tiles per CU, balanced).
// EXACT round-10 champion (81.2 us): swapped QK^T -> packed uint2 P-writes,
// T14 register prefetch, vexp2 pre-folded scale, pair-pack bf16, mask
// unswitched to diagonal tile. Constraints: VGPR<=64, LDS 27.6K, K/V
// LDS-staged, no setprio, no per-wave q doubling.
#define LDP 72   // padded row stride (shorts): 144 B breaks the 128 B conflict
__global__ __launch_bounds__(256) void attn_flash(
    const unsigned short* __restrict__ qkv,
    const unsigned short* __restrict__ Vt,
    unsigned short* __restrict__ X2)
{
    __shared__ __align__(16) unsigned short Ks[64 * LDP];      // [kv][d]
    __shared__ __align__(16) unsigned short Vs[64 * LDP];      // [d][kv]
    __shared__ __align__(16) unsigned short Ps[4 * 16 * LDP];  // per-wave [16 q][64 kv]
    const int tid  = threadIdx.x;
    const int wave = tid >> 6, lane = tid & 63;
    const int q4 = lane >> 4, l16 = lane & 15;
    const int h  = blockIdx.y;

    // balanced q-tile mapping: head-group k gets {x, 63-x, x+16, 47-x}
    const int x = blockIdx.x, hg = blockIdx.y >> 2;
    int qt;
    if      (hg == 0) qt = x;
    else if (hg == 1) qt = 63 - x;
    else if (hg == 2) qt = (x + 16) & 63;
    else              qt = (47 - x) & 63;
    const int q0 = qt * 64;

    // Q frags (A/B layouts match: idx = lane&15, k = quad*8+j)
    bf16x8 aq[2];
    {
        const unsigned short* qp =
            qkv + (size_t)(q0 + wave * 16 + l16) * N3 + h * HDIM + q4 * 8;
        aq[0] = *(const bf16x8*)(qp);
        aq[1] = *(const bf16x8*)(qp + 32);
    }

    float l_part = 0.f;
    f32x4 o[4] = {};

    const int rr = tid >> 3;        // 0..31
    const int cc = (tid & 7) * 8;   // 0..56
    const int ntile = qt + 1;
    const int grow = q0 + wave * 16 + l16;   // this lane's q row (swapped layout)

    const float SCL = 0.18033688f;  // 0.125 * log2(e)

    // prefetch tile 0 into registers
    uint4 kv_a, kv_b, vt_a, vt_b;
    {
        kv_a = *(const uint4*)&qkv[(size_t)(rr)      * N3 + D_EMB + h * HDIM + cc];
        kv_b = *(const uint4*)&qkv[(size_t)(32 + rr) * N3 + D_EMB + h * HDIM + cc];
        vt_a = *(const uint4*)&Vt [(size_t)(h * HDIM + rr)      * S_LEN + cc];
        vt_b = *(const uint4*)&Vt [(size_t)(h * HDIM + 32 + rr) * S_LEN + cc];
    }

    for (int t = 0; t < ntile; ++t) {
        const int kv0 = t * 64;
        __syncthreads();   // prior tile's LDS reads complete
        *(uint4*)&Ks[rr * LDP + cc]        = kv_a;
        *(uint4*)&Ks[(32 + rr) * LDP + cc] = kv_b;
        *(uint4*)&Vs[rr * LDP + cc]        = vt_a;
        *(uint4*)&Vs[(32 + rr) * LDP + cc] = vt_b;
        // issue next tile's loads now; compute below hides their latency
        if (t + 1 < ntile) {
            const int kn = kv0 + 64;
            kv_a = *(const uint4*)&qkv[(size_t)(kn + rr)      * N3 + D_EMB + h * HDIM + cc];
            kv_b = *(const uint4*)&qkv[(size_t)(kn + 32 + rr) * N3 + D_EMB + h * HDIM + cc];
            vt_a = *(const uint4*)&Vt [(size_t)(h * HDIM + rr)      * S_LEN + kn + cc];
            vt_b = *(const uint4*)&Vt [(size_t)(h * HDIM + 32 + rr) * S_LEN + kn + cc];
        }
        __syncthreads();

        // S^T = K Q^T (A = K rows (m=kv), B = Q (n=q))
        f32x4 sacc[4] = {};
#pragma unroll
        for (int kk = 0; kk < 2; ++kk)
#pragma unroll
            for (int nt = 0; nt < 4; ++nt) {
                bf16x8 kf = *(const bf16x8*)&Ks[(nt * 16 + l16) * LDP + kk * 32 + q4 * 8];
                sacc[nt] = __builtin_amdgcn_mfma_f32_16x16x32_bf16(
                    kf, aq[kk], sacc[nt], 0, 0, 0);
            }

        // softmax-lite; mask only on the diagonal tile
        if (t != ntile - 1) {
#pragma unroll
            for (int nt = 0; nt < 4; ++nt) {
                float e0 = vexp2(sacc[nt][0] * SCL);
                float e1 = vexp2(sacc[nt][1] * SCL);
                float e2 = vexp2(sacc[nt][2] * SCL);
                float e3 = vexp2(sacc[nt][3] * SCL);
                l_part += e0; l_part += e1; l_part += e2; l_part += e3;
                uint2 pk;
                pk.x = pkbf(e0, e1);
                pk.y = pkbf(e2, e3);
                *(uint2*)&Ps[wave * 16 * LDP + l16 * LDP + nt * 16 + q4 * 4] = pk;
            }
        } else {
#pragma unroll
            for (int nt = 0; nt < 4; ++nt) {
                float e[4];
#pragma unroll
                for (int r = 0; r < 4; ++r) {
                    e[r] = vexp2(sacc[nt][r] * SCL);
                    if (kv0 + nt * 16 + q4 * 4 + r > grow) e[r] = 0.f;
                    l_part += e[r];
                }
                uint2 pk;
                pk.x = pkbf(e[0], e[1]);
                pk.y = pkbf(e[2], e[3]);
                *(uint2*)&Ps[wave * 16 * LDP + l16 * LDP + nt * 16 + q4 * 4] = pk;
            }
        }
        // per-wave LDS roundtrip: only need this wave's writes visible
        __asm__ volatile("s_waitcnt lgkmcnt(0)" ::: "memory");

        // O += P V
#pragma unroll
        for (int kk = 0; kk < 2; ++kk) {
            bf16x8 pa = *(const bf16x8*)&Ps[wave * 16 * LDP + l16 * LDP + kk * 32 + q4 * 8];
#pragma unroll
            for (int dt = 0; dt < 4; ++dt) {
                bf16x8 vb = *(const bf16x8*)&Vs[(dt * 16 + l16) * LDP + kk * 32 + q4 * 8];
                o[dt] = __builtin_amdgcn_mfma_f32_16x16x32_bf16(
                    pa, vb, o[dt], 0, 0, 0);
            }
        }
    }

    // row-sum: lane holds partial for q = l16; reduce across the 4 quads
    float l = l_part;
    l += __shfl_xor(l, 16);
    l += __shfl_xor(l, 32);
    float linv[4];
#pragma unroll
    for (int r = 0; r < 4; ++r)
        linv[r] = 1.f / __shfl(l, q4 * 4 + r);

#pragma unroll
    for (int dt = 0; dt < 4; ++dt)
#pragma unroll
        for (int r = 0; r < 4; ++r) {
            const int row = q0 + wave * 16 + q4 * 4 + r;
            X2[(size_t)row * D_EMB + h * HDIM + dt * 16 + l16] =
                f2bf(o[dt][r] * linv[r]);
        }
}

extern "C" void kernel_launch(void* const* d_in, const int* in_sizes, int n_in,
                              void* d_out, int out_size, void* d_ws, size_t ws_size,
                              hipStream_t stream) {
    const float* x     = (const float*)d_in[0];   // [4096][1024] fp32
    const float* w_qkv = (const float*)d_in[1];   // [1024][3072] fp32
    const float* b_qkv = (const float*)d_in[2];   // [3072] fp32
    const float* w_out = (const float*)d_in[3];   // [1024][1024] fp32
    const float* b_out = (const float*)d_in[4];   // [1024] fp32
    float* out = (float*)d_out;                   // [4096][1024] fp32

    char* ws = (char*)d_ws;
    unsigned short* qkv   = (unsigned short*)(ws);              // 24 MB
    unsigned short* wqkvT = (unsigned short*)(ws + 25165824);   //  6 MB
    unsigned short* woutT = (unsigned short*)(ws + 31457280);   //  2 MB
    unsigned short* Vt    = (unsigned short*)(ws + 33554432);   //  8 MB
    unsigned short* X2    = (unsigned short*)(ws + 41943040);   //  8 MB
    unsigned short* Xb    = X2;  // aliased: Xb consumed by GEMM1 before attn writes X2

    // x -> bf16 convert + both weight transposes, ONE launch (r14)
    prologue<<<6144, 256, 0, stream>>>(x, Xb, w_qkv, w_out, wqkvT, woutT);

    // qkv = Xb @ w_qkv + b_qkv  (bf16 out), 128x128 tiles, pipelined (r8)
    gemm_bt_bias<false, 128><<<dim3(3072 / 128, 4096 / 128), 256, 0, stream>>>(
        Xb, wqkvT, b_qkv, qkv, 4096, 3072, 1024);

    // Vt[h*64+d][s] = V[s][h*64+d]
    transpose_bf16<<<dim3(1024 / 32, 4096 / 32), dim3(32, 8), 0, stream>>>(
        qkv, Vt, 4096, 3072, 2048);

    // causal flash attention -> X2 [S][1024] bf16
    attn_flash<<<dim3(64, 16), 256, 0, stream>>>(qkv, Vt, X2);

    // out = X2 @ w_out + b_out  (fp32 out), 64x128 tiles, pipelined (r8)
    gemm_bt_bias<true, 64><<<dim3(1024 / 128, 4096 / 64), 256, 0, stream>>>(
        X2, woutT, b_out, out, 4096, 1024, 1024);
}